// Round 9
// baseline (1129.084 us; speedup 1.0000x reference)
//
#include <hip/hip_runtime.h>
#include <hip/hip_bf16.h>

// Gramba (fp32 in / fp32 out): x_in = silu(x@W1+b1); x_skip = silu(x@W2+b2)
//         z = sigmoid(x_in@Wz+bz); h~ = x_in@Wh+bh
//         h = scan(h = (1-z)h + z*h~); out = (x_skip+h)@Wo + bo
// R9: CS=512, 8 chunks, rawzh double-buffered (2x16 MiB in [0,32)).
// scan(c) FUSED into zh-GEMM(c+1) dispatch (independent block ranges) --
// scan cost hidden under GEMM. Prologue (conv + 5 transposes) fused into
// one kernel. GEMM: R8 structure (dbuf K-loop, vmcnt(4), XOR-swizzled LDS,
// LDS-staged coalesced bf16 epilogue).
//
// Workspace layout (183 MiB, proven):
//   [0,16)    rawzh buf0 (bf16 2048x4096)  [xb overlays before zh(0)]
//   [16,32)   rawzh buf1
//   [32,33)   carry (fp32 4x2048)
//   [33,97)   xin   (bf16 16384x2048)
//   [97,161)  xskip (bf16; scan adds h in place)
//   [161,165) Wt12  [165,181) Wtzh  [181,183) Wto

typedef __bf16 bf16x8 __attribute__((ext_vector_type(8)));
typedef __bf16 bf16x4 __attribute__((ext_vector_type(4)));
typedef float  f32x4  __attribute__((ext_vector_type(4)));

#define DEVINL __device__ __forceinline__

DEVINL void async_ld16(const __bf16* g, __bf16* l) {
    __builtin_amdgcn_global_load_lds(
        (const __attribute__((address_space(1))) void*)g,
        (__attribute__((address_space(3))) void*)l, 16, 0, 0);
}

DEVINL float fsigmoid(float v) { return 1.0f / (1.0f + __expf(-v)); }

struct SMem {
    union {
        struct { __bf16 A[2][128 * 32]; __bf16 B[2][128 * 32]; } kl;  // 32 KB
        __bf16 ct[128 * 144];                                         // 36 KB
        struct { float Als[4][64]; float Bls[4][64]; } sc;            //  2 KB
    };
};

// MODE 0: dual split-silu bf16 (out/out2, stride 2048) | MODE 3: fp32 out
// MODE 4: bf16 out, dual bias split at 2048
template <int MODE>
DEVINL void gemm_body(SMem& sm, int bx, int by,
                      const __bf16* __restrict__ A, const __bf16* __restrict__ Bt,
                      const float* __restrict__ bias, const float* __restrict__ bias2,
                      void* __restrict__ out, void* __restrict__ out2, int N, int K,
                      int bps, int seg_stride, int row_off)
{
    const int tid = threadIdx.x;
    const int seg = bx / bps;
    const int within = bx - seg * bps;
    const int gm0 = row_off + seg * seg_stride + within * 128;
    const int om0 = bx * 128;
    const int n0 = by * 128;

    const int c0 = tid, c1 = tid + 256;
    const int r0 = c0 >> 2, k0 = (c0 & 3) ^ ((c0 >> 3) & 3);
    const int r1 = c1 >> 2, k1 = (c1 & 3) ^ ((c1 >> 3) & 3);
    const __bf16* Ag0 = A  + (size_t)(gm0 + r0) * K + k0 * 8;
    const __bf16* Ag1 = A  + (size_t)(gm0 + r1) * K + k1 * 8;
    const __bf16* Bg0 = Bt + (size_t)(n0 + r0) * K + k0 * 8;
    const __bf16* Bg1 = Bt + (size_t)(n0 + r1) * K + k1 * 8;

    const int lane = tid & 63;
    const int wave = tid >> 6;
    const int wrow = (wave >> 1) * 64;
    const int wcol = (wave & 1) * 64;
    const int quad = lane >> 4;
    const int r = lane & 15;
    const int swz = (quad ^ ((r >> 1) & 3)) * 8;

    f32x4 acc[4][4] = {};

    const int T = K >> 5;
    async_ld16(Ag0, sm.kl.A[0] + c0 * 8);
    async_ld16(Ag1, sm.kl.A[0] + c1 * 8);
    async_ld16(Bg0, sm.kl.B[0] + c0 * 8);
    async_ld16(Bg1, sm.kl.B[0] + c1 * 8);

    for (int t = 0; t < T; ++t) {
        const int cur = t & 1;
        if (t + 1 < T) {
            const int kt = (t + 1) << 5;
            async_ld16(Ag0 + kt, sm.kl.A[cur ^ 1] + c0 * 8);
            async_ld16(Ag1 + kt, sm.kl.A[cur ^ 1] + c1 * 8);
            async_ld16(Bg0 + kt, sm.kl.B[cur ^ 1] + c0 * 8);
            async_ld16(Bg1 + kt, sm.kl.B[cur ^ 1] + c1 * 8);
            asm volatile("s_waitcnt vmcnt(4)\n\ts_barrier" ::: "memory");
        } else {
            asm volatile("s_waitcnt vmcnt(0)\n\ts_barrier" ::: "memory");
        }

        const __bf16* ap = sm.kl.A[cur] + (wrow + r) * 32 + swz;
        const __bf16* bp = sm.kl.B[cur] + (wcol + r) * 32 + swz;
        bf16x8 af[4], bf_[4];
#pragma unroll
        for (int i = 0; i < 4; ++i) af[i] = *(const bf16x8*)(ap + i * 512);
#pragma unroll
        for (int i = 0; i < 4; ++i) bf_[i] = *(const bf16x8*)(bp + i * 512);
#pragma unroll
        for (int i = 0; i < 4; ++i)
#pragma unroll
            for (int j = 0; j < 4; ++j)
                acc[i][j] = __builtin_amdgcn_mfma_f32_16x16x32_bf16(
                    af[i], bf_[j], acc[i][j], 0, 0, 0);

        asm volatile("s_waitcnt lgkmcnt(0)\n\ts_barrier" ::: "memory");
    }

    // C/D layout (m89): col = lane&15, row = (lane>>4)*4 + reg
    if (MODE == 3) {
#pragma unroll
        for (int i = 0; i < 4; ++i)
#pragma unroll
            for (int j = 0; j < 4; ++j) {
                const int or0 = om0 + wrow + i * 16 + quad * 4;
                const int gc  = n0 + wcol + j * 16 + r;
                const float bv = bias[gc];
#pragma unroll
                for (int k = 0; k < 4; ++k)
                    ((float*)out)[(size_t)(or0 + k) * N + gc] = acc[i][j][k] + bv;
            }
    } else {
        const bool lo = n0 < 2048;
#pragma unroll
        for (int i = 0; i < 4; ++i)
#pragma unroll
            for (int j = 0; j < 4; ++j) {
                const int gc = n0 + wcol + j * 16 + r;
                const float bv = lo ? bias[gc] : bias2[gc - 2048];
#pragma unroll
                for (int k = 0; k < 4; ++k) {
                    const float v = acc[i][j][k] + bv;
                    const __bf16 o = (MODE == 0) ? (__bf16)(v * fsigmoid(v))
                                                 : (__bf16)v;
                    sm.ct[(wrow + i * 16 + quad * 4 + k) * 144 +
                          (wcol + j * 16 + r)] = o;
                }
            }
        __syncthreads();
        __bf16* dst;
        int cb;
        size_t stride;
        if (MODE == 0) {
            dst = lo ? (__bf16*)out : (__bf16*)out2;
            cb = lo ? n0 : n0 - 2048;
            stride = 2048;
        } else {
            dst = (__bf16*)out;
            cb = n0;
            stride = (size_t)N;
        }
        const int tr = tid >> 4;
        const int tc = (tid & 15) * 8;
#pragma unroll
        for (int p = 0; p < 8; ++p) {
            const int row = p * 16 + tr;
            const bf16x8 vv = *(const bf16x8*)(sm.ct + row * 144 + tc);
            *(bf16x8*)(dst + (size_t)(om0 + row) * stride + cb + tc) = vv;
        }
    }
}

// Scan body, 256 threads: 64 channels (lane) x 4 waves (CS/4-step segments).
// raw [B*CS][4096]: z cols 0..2047, h~ cols 2048..4095 (pre-activation).
DEVINL void scan_body(SMem& sm, int sb, const __bf16* __restrict__ raw,
                      __bf16* __restrict__ xskip, float* __restrict__ carry,
                      int CS, int S, int t0, int first)
{
    const int lane = threadIdx.x & 63;
    const int w = threadIdx.x >> 6;            // 0..3
    const int gpb = 2048 >> 6;                 // 32
    const int batch = sb / gpb;
    const int col = (sb - batch * gpb) * 64 + lane;
    const int L = CS >> 2;                     // 128
    const int tbeg = w * L;
    const size_t rbase = ((size_t)batch * CS + tbeg) * 4096 + col;

    float A = 1.0f, Bv = 0.0f;
    {
        size_t idx = rbase;
#pragma unroll 8
        for (int t = 0; t < L; ++t, idx += 4096) {
            const float z = fsigmoid((float)raw[idx]);
            const float b = z * (float)raw[idx + 2048];
            const float a = 1.0f - z;
            Bv = a * Bv + b;
            A *= a;
        }
    }
    sm.sc.Als[w][lane] = A;
    sm.sc.Bls[w][lane] = Bv;
    __syncthreads();

    const int ch = batch * 2048 + col;
    float h = first ? 0.0f : carry[ch];
#pragma unroll
    for (int s = 0; s < 3; ++s)
        if (s < w) h = sm.sc.Als[s][lane] * h + sm.sc.Bls[s][lane];
    if (w == 3)
        carry[ch] = A * h + Bv;

    {
        size_t idx = rbase;
        size_t gidx = ((size_t)batch * S + t0 + tbeg) * 2048 + col;
#pragma unroll 8
        for (int t = 0; t < L; ++t, idx += 4096, gidx += 2048) {
            const float z = fsigmoid((float)raw[idx]);
            const float b = z * (float)raw[idx + 2048];
            h = (1.0f - z) * h + b;
            xskip[gidx] = (__bf16)((float)xskip[gidx] + h);
        }
    }
}

template <int MODE>
__global__ __launch_bounds__(256)
void gemm_bt(const __bf16* __restrict__ A, const __bf16* __restrict__ Bt,
             const float* __restrict__ bias, const float* __restrict__ bias2,
             void* __restrict__ out, void* __restrict__ out2, int N, int K,
             int bps, int seg_stride, int row_off)
{
    __shared__ SMem sm;
    gemm_body<MODE>(sm, blockIdx.x, blockIdx.y, A, Bt, bias, bias2,
                    out, out2, N, K, bps, seg_stride, row_off);
}

// Fused: blocks [0,nGemm) = zh-GEMM for chunk c+1; rest = scan for chunk c.
__global__ __launch_bounds__(256)
void zh_scan(const __bf16* __restrict__ xin, const __bf16* __restrict__ Wtzh,
             const float* __restrict__ bz, const float* __restrict__ bh,
             __bf16* __restrict__ rawG, const __bf16* __restrict__ rawS,
             __bf16* __restrict__ xskip, float* __restrict__ carry,
             int nGemm, int gemmBX, int bpsG, int rowOffG,
             int CS, int S, int t0S, int firstS)
{
    __shared__ SMem sm;
    const int bid = blockIdx.x;
    if (bid < nGemm) {
        const int bx = bid % gemmBX;
        const int by = bid / gemmBX;
        gemm_body<4>(sm, bx, by, xin, Wtzh, bz, bh, rawG, nullptr,
                     4096, 2048, bpsG, S, rowOffG);
    } else {
        scan_body(sm, bid - nGemm, rawS, xskip, carry, CS, S, t0S, firstS);
    }
}

// Fused prologue: conv x -> bf16 (blocks 0..8191) + 5 weight transposes.
__global__ __launch_bounds__(256)
void prep(const float* __restrict__ x, __bf16* __restrict__ xb,
          const float* __restrict__ W1, const float* __restrict__ W2,
          const float* __restrict__ Wz, const float* __restrict__ Wh,
          const float* __restrict__ Wo,
          __bf16* __restrict__ Wt12, __bf16* __restrict__ Wtzh,
          __bf16* __restrict__ Wto)
{
    __shared__ float tile[32][33];
    const int bid = blockIdx.x;
    const int tid = threadIdx.x;
    if (bid < 8192) {
        const int i = bid * 256 + tid;      // n4 = 16384*512/4 = 2097152 exact
        const float4 v = ((const float4*)x)[i];
        bf16x4 o;
        o[0] = (__bf16)v.x; o[1] = (__bf16)v.y; o[2] = (__bf16)v.z; o[3] = (__bf16)v.w;
        ((bf16x4*)xb)[i] = o;
        return;
    }
    int t = bid - 8192;
    const float* src; __bf16* dst; int K, N;
    if (t < 1024)       { src = W1; dst = Wt12;                        K = 512;  N = 2048; }
    else if (t < 2048)  { t -= 1024; src = W2; dst = Wt12 + 2048 * 512; K = 512;  N = 2048; }
    else if (t < 6144)  { t -= 2048; src = Wz; dst = Wtzh;             K = 2048; N = 2048; }
    else if (t < 10240) { t -= 6144; src = Wh; dst = Wtzh + 2048 * 2048; K = 2048; N = 2048; }
    else                { t -= 10240; src = Wo; dst = Wto;             K = 2048; N = 512; }
    const int nbCnt = N >> 5;
    const int nb = (t % nbCnt) * 32;
    const int kb = (t / nbCnt) * 32;
    const int tx = tid & 31;
    const int ty = tid >> 5;
#pragma unroll
    for (int i = 0; i < 32; i += 8)
        tile[ty + i][tx] = src[(size_t)(kb + ty + i) * N + nb + tx];
    __syncthreads();
#pragma unroll
    for (int i = 0; i < 32; i += 8)
        dst[(size_t)(nb + ty + i) * K + kb + tx] = (__bf16)tile[tx][ty + i];
}

extern "C" void kernel_launch(void* const* d_in, const int* in_sizes, int n_in,
                              void* d_out, int out_size, void* d_ws, size_t ws_size,
                              hipStream_t stream)
{
    const float* x     = (const float*)d_in[0];
    const float* W_in1 = (const float*)d_in[1];
    const float* b_in1 = (const float*)d_in[2];
    const float* W_in2 = (const float*)d_in[3];
    const float* b_in2 = (const float*)d_in[4];
    const float* W_z   = (const float*)d_in[5];
    const float* b_z   = (const float*)d_in[6];
    const float* W_h   = (const float*)d_in[7];
    const float* b_h   = (const float*)d_in[8];
    const float* W_out = (const float*)d_in[9];
    const float* b_out = (const float*)d_in[10];

    const int B = 4, S = 4096, H = 512, E = 2048;
    const int M = B * S;        // 16384
    const int CS = 512;         // chunk length
    const int NC = S / CS;      // 8 chunks
    const int MC = B * CS;      // 2048 rows per chunk
    const int GB = (MC / 128) * (2 * E / 128);   // 16*32 = 512 gemm blocks
    const int SB = B * E / 64;                   // 128 scan blocks

    const size_t MiB = 1024 * 1024;
    if (ws_size < 183 * MiB) return;

    char* ws = (char*)d_ws;
    __bf16* xb    = (__bf16*)(ws + 0);        // overlaid by rawzh[0]
    __bf16* raw0  = (__bf16*)(ws + 0);
    __bf16* raw1  = (__bf16*)(ws + 16 * MiB);
    float*  carry = (float*) (ws + 32 * MiB);
    __bf16* xin   = (__bf16*)(ws + 33 * MiB);
    __bf16* xskip = (__bf16*)(ws + 97 * MiB);
    __bf16* Wt12  = (__bf16*)(ws + 161 * MiB);
    __bf16* Wtzh  = (__bf16*)(ws + 165 * MiB);
    __bf16* Wto   = (__bf16*)(ws + 181 * MiB);
    __bf16* rawb[2] = { raw0, raw1 };

    prep<<<19456, 256, 0, stream>>>(x, xb, W_in1, W_in2, W_z, W_h, W_out,
                                    Wt12, Wtzh, Wto);

    // Merged input GEMM: N=4096 (W1|W2), split-silu -> xin / xskip
    gemm_bt<0><<<dim3(M / 128, 2 * E / 128), 256, 0, stream>>>(
        xb, Wt12, b_in1, b_in2, xin, xskip, 2 * E, H, M / 128, 0, 0);

    // Recurrent stage: dispatch i runs zh-GEMM(chunk i) + scan(chunk i-1)
    for (int i = 0; i <= NC; ++i) {
        const int nG = (i < NC) ? GB : 0;
        const int nS = (i > 0) ? SB : 0;
        zh_scan<<<nG + nS, 256, 0, stream>>>(
            xin, Wtzh, b_z, b_h,
            rawb[i & 1], rawb[(i - 1) & 1], xskip, carry,
            nG, MC / 128, CS / 128, i * CS,
            CS, S, (i - 1) * CS, i == 1);
    }

    // Output GEMM (full M), fp32 out
    gemm_bt<3><<<dim3(M / 128, H / 128), 256, 0, stream>>>(
        xskip, Wto, b_out, nullptr, (float*)d_out, nullptr, H, E, M / 128, 0, 0);
}